// Round 1
// 396.517 us; speedup vs baseline: 1.0323x; 1.0323x over previous
//
#include <hip/hip_runtime.h>
#include <cfloat>

#define NB      20   // NUM_BINS
#define NBOUND  19   // NUM_BINS - 1
#define ED      768  // EMBED_DIM
#define EPS     1e-8f

typedef float vf4 __attribute__((ext_vector_type(4)));

// ---------------------------------------------------------------------------
// Kernel A: one THREAD per batch row. Coalesced values/code_ids loads,
// 19-element linear scan over L2-resident boundaries (all loads independent,
// fully unrolled), pack {alpha, lower|upper<<8} into an 8B record.
// ---------------------------------------------------------------------------
__global__ __launch_bounds__(256) void sde_search(
    const float* __restrict__ values,
    const int*   __restrict__ code_ids,
    const float* __restrict__ boundaries,
    uint2*       __restrict__ recs,
    int batch)
{
    const int i = blockIdx.x * 256 + threadIdx.x;
    if (i >= batch) return;

    const float v = values[i];
    const int   c = code_ids[i];
    const float* __restrict__ br = boundaries + (size_t)c * NBOUND;

    // searchsorted(side='left'): count of boundaries strictly < v
    int idx = 0;
    #pragma unroll
    for (int j = 0; j < NBOUND; ++j) idx += (br[j] < v) ? 1 : 0;
    // idx in [0, 19]

    int lo_i = idx - 1; lo_i = lo_i < 0 ? 0 : lo_i;            // clip(idx-1,0,18)
    int hi_i = idx > NBOUND - 1 ? NBOUND - 1 : idx;            // clip(idx,  0,18)
    const float lo_b = br[lo_i];
    const float hi_b = br[hi_i];

    const bool interior = (idx > 0) && (idx < NB - 1);
    const float denom = hi_b - lo_b;
    const bool tiny = fabsf(denom) < EPS;

    float alpha = (v - lo_b) / (tiny ? 1.0f : denom);
    alpha = fminf(fmaxf(alpha, 0.0f), 1.0f);
    if (tiny)      alpha = 0.5f;
    if (!interior) alpha = 0.0f;

    const int lower = (idx == 0) ? 0 : ((idx >= NB - 1) ? NB - 1 : idx - 1);
    const int upper = interior ? idx : lower;

    uint2 r;
    r.x = __float_as_uint(alpha);
    r.y = (unsigned)lower | ((unsigned)upper << 8);
    recs[i] = r;
}

// ---------------------------------------------------------------------------
// Kernel B: one WAVE per batch row — pure streamer. Front-end is a single 8B
// broadcast load (all 64 lanes same address -> one request) + a few ALU ops,
// then 6 coalesced 1KB embed loads (L1/L2-resident table) and 3 coalesced
// 1KB nontemporal stores.
// ---------------------------------------------------------------------------
__global__ __launch_bounds__(256) void sde_interp(
    const uint2* __restrict__ recs,
    const float* __restrict__ embed_table,
    float*       __restrict__ out,
    int batch)
{
    const int wave = blockIdx.x * (blockDim.x >> 6) + (threadIdx.x >> 6);
    const int lane = threadIdx.x & 63;
    if (wave >= batch) return;

    const uint2 rec = recs[wave];                 // wave-uniform broadcast
    const float alpha = __uint_as_float(rec.x);
    const int   lower = (int)(rec.y & 0xffu);
    const int   upper = (int)((rec.y >> 8) & 0xffu);

    const vf4* __restrict__ tlo = (const vf4*)(embed_table + (size_t)lower * ED);
    const vf4* __restrict__ thi = (const vf4*)(embed_table + (size_t)upper * ED);
    vf4* __restrict__ orow = (vf4*)(out + (size_t)wave * ED);

    const float om = 1.0f - alpha;
    #pragma unroll
    for (int k = 0; k < 3; ++k) {
        const int s = lane + k * 64;
        const vf4 e0 = tlo[s];
        const vf4 e1 = thi[s];
        vf4 r;
        r.x = om * e0.x + alpha * e1.x;
        r.y = om * e0.y + alpha * e1.y;
        r.z = om * e0.z + alpha * e1.z;
        r.w = om * e0.w + alpha * e1.w;
        __builtin_nontemporal_store(r, &orow[s]);   // bypass L2 pollution
    }
}

// ---------------------------------------------------------------------------
// Fallback: previous fused wave-per-row kernel (used only if ws too small).
// ---------------------------------------------------------------------------
__global__ __launch_bounds__(256) void sde_kernel(
    const float* __restrict__ values,
    const int*   __restrict__ code_ids,
    const float* __restrict__ boundaries,
    const float* __restrict__ embed_table,
    float*       __restrict__ out,
    int batch)
{
    const int wave = blockIdx.x * (blockDim.x >> 6) + (threadIdx.x >> 6);
    const int lane = threadIdx.x & 63;
    if (wave >= batch) return;
    const int b = wave;

    const float v = values[b];
    const int   c = code_ids[b];

    float bnd = FLT_MAX;
    if (lane < NBOUND) bnd = boundaries[(size_t)c * NBOUND + lane];

    const unsigned long long lt = __ballot(bnd < v);
    const int idx = __popcll(lt);

    int lo_i = idx - 1; lo_i = lo_i < 0 ? 0 : lo_i;
    int hi_i = idx > NBOUND - 1 ? NBOUND - 1 : idx;
    const float lo_b = __shfl(bnd, lo_i);
    const float hi_b = __shfl(bnd, hi_i);

    const bool interior = (idx > 0) && (idx < NB - 1);
    const float denom = hi_b - lo_b;
    const bool tiny = fabsf(denom) < EPS;

    float alpha = (v - lo_b) / (tiny ? 1.0f : denom);
    alpha = fminf(fmaxf(alpha, 0.0f), 1.0f);
    if (tiny)      alpha = 0.5f;
    if (!interior) alpha = 0.0f;

    const int lower = (idx == 0) ? 0 : ((idx >= NB - 1) ? NB - 1 : idx - 1);
    const int upper = interior ? idx : lower;

    const float4* __restrict__ tlo = (const float4*)(embed_table + (size_t)lower * ED);
    const float4* __restrict__ thi = (const float4*)(embed_table + (size_t)upper * ED);
    float4* __restrict__ orow = (float4*)(out + (size_t)b * ED);

    const float om = 1.0f - alpha;
    #pragma unroll
    for (int k = 0; k < 3; ++k) {
        const int s = lane + k * 64;
        const float4 e0 = tlo[s];
        const float4 e1 = thi[s];
        float4 r;
        r.x = om * e0.x + alpha * e1.x;
        r.y = om * e0.y + alpha * e1.y;
        r.z = om * e0.z + alpha * e1.z;
        r.w = om * e0.w + alpha * e1.w;
        orow[s] = r;
    }
}

extern "C" void kernel_launch(void* const* d_in, const int* in_sizes, int n_in,
                              void* d_out, int out_size, void* d_ws, size_t ws_size,
                              hipStream_t stream)
{
    const float* values     = (const float*)d_in[0];
    const int*   code_ids   = (const int*)  d_in[1];
    const float* boundaries = (const float*)d_in[2];
    const float* embed      = (const float*)d_in[3];
    float*       out        = (float*)d_out;

    const int batch = in_sizes[0];

    if (d_ws != nullptr && ws_size >= (size_t)batch * sizeof(uint2)) {
        uint2* recs = (uint2*)d_ws;
        const int blocksA = (batch + 255) / 256;
        sde_search<<<blocksA, 256, 0, stream>>>(values, code_ids, boundaries, recs, batch);

        const int waves_per_block = 4;    // 256 threads
        const int blocksB = (batch + waves_per_block - 1) / waves_per_block;
        sde_interp<<<blocksB, 256, 0, stream>>>(recs, embed, out, batch);
    } else {
        const int waves_per_block = 4;
        const int blocks = (batch + waves_per_block - 1) / waves_per_block;
        sde_kernel<<<blocks, 256, 0, stream>>>(values, code_ids, boundaries, embed, out, batch);
    }
}